// Round 11
// baseline (179.340 us; speedup 1.0000x reference)
//
#include <hip/hip_runtime.h>

// Involution: B=16, C=256, H=W=56, mid=64, GROUPS=16, GROUP_SIZE=16, K=3 (KK=9)
// All fp32. Output (16,256,56,56).
//
// This revision:
//  conv1     : unchanged from round-10 (best measured: acc[16] + triple
//              buffer + counted vmcnt).
//  conv2_inv : REWRITTEN as one-wave blocks, NO LDS, NO barriers.
//              Each lane holds its own t column in registers (2x32 chunks,
//              loaded via uniform-base + 32-bit lane offset -> SGPR-folded
//              addressing, the win R8's ablation exposed without buffer-
//              intrinsic ordering pessimism). Grid 784 pc x 16 g = 12544,
//              XCD remap keeps all 16 g-waves of a chunk on the t-writer's
//              XCD L2. launch_bounds(64,4) -> 16 waves/CU.

#define Cn    256
#define MID   64
#define Hn    56
#define Wn    56
#define HW    3136
#define Bn    16
#define NPIX  (Bn * HW)       // 50176
#define CHW   (Cn * HW)
#define NKK   9
#define NG    16
#define GSZ   16
#define PXT   64              // pixels per chunk (49 chunks/batch, 784 total)
#define BN_EPS 1e-5f

// async global->LDS: per-lane global src, wave-uniform LDS base + lane*size
#define GLOAD_LDS(src, dst, sz)                                                        \
  __builtin_amdgcn_global_load_lds(                                                    \
      (const __attribute__((address_space(1))) void*)(src),                            \
      (__attribute__((address_space(3))) void*)(dst), (sz), 0, 0)

// ---------------------------------------------------------------------------
// prep: w1f[c*64+o] = w1[o*256+c] * scale[o];  bias1[o] = beta[o]-mean[o]*scale[o]
// ---------------------------------------------------------------------------
__global__ __launch_bounds__(256) void prep_kernel(
    const float* __restrict__ w1,
    const float* __restrict__ gamma,
    const float* __restrict__ beta,
    const float* __restrict__ mean,
    const float* __restrict__ var,
    float* __restrict__ w1f,
    float* __restrict__ bias1) {
  int idx = blockIdx.x * 256 + threadIdx.x;
  if (idx < MID * Cn) {
    int c = idx >> 6;
    int o = idx & 63;
    float scale = gamma[o] / sqrtf(var[o] + BN_EPS);
    w1f[idx] = w1[o * Cn + c] * scale;
  } else if (idx < MID * Cn + MID) {
    int o = idx - MID * Cn;
    float scale = gamma[o] / sqrtf(var[o] + BN_EPS);
    bias1[o] = beta[o] - mean[o] * scale;
  }
}

// ---------------------------------------------------------------------------
// conv1: t[o][px] = relu(bias1[o] + sum_c x[b,c,px] * w1f[c*64+o])
// Block = 64 px x ALL 64 outputs (grid 784). Wave wv -> outputs wv*16..+15.
// Per c: 1 ds_read_b32 (x) + 4 wave-uniform s_load_dwordx4 (weights) + 16 FMA.
// x tiles: TRIPLE-buffered LDS, counted vmcnt(1) -> loads span barriers.
// ---------------------------------------------------------------------------
__global__ __launch_bounds__(256) void conv1_kernel(
    const float* __restrict__ x,
    const float* __restrict__ w1f,
    const float* __restrict__ bias1,
    float* __restrict__ t) {
  __shared__ __align__(16) float lx[3][16][PXT];   // 12 KB triple buffer

  const int tid = threadIdx.x;
  const int px  = tid & 63;
  const int wv  = __builtin_amdgcn_readfirstlane(tid >> 6);   // 0..3

  const int bid = blockIdx.x;          // pc == bid; XCD = bid%8 (matches conv2)
  const int px0 = bid * PXT;
  const int b   = px0 / HW;
  const int hw0 = px0 - b * HW;
  const float* xb = x + (size_t)b * CHW + hw0;

  const int rsub = px >> 4;            // 0..3
  const int csub = (px & 15) << 2;     // 0,4,..,60
  const int lrow = (wv << 2) + rsub;   // lane's row within the 16-row tile

  // prologue: issue tiles 0 and 1 (stay in flight into the loop)
  GLOAD_LDS(xb + (size_t)lrow * HW + csub, &lx[0][wv << 2][0], 16);
  GLOAD_LDS(xb + (size_t)(16 + lrow) * HW + csub, &lx[1][wv << 2][0], 16);

  float acc[16];
#pragma unroll
  for (int j = 0; j < 16; ++j) acc[j] = 0.0f;

  for (int k = 0; k < 16; ++k) {
    // wait tile k only; tile k+1's load stays outstanding (counted vmcnt).
    if (k < 15) {
      asm volatile("s_waitcnt vmcnt(1)" ::: "memory");
    } else {
      asm volatile("s_waitcnt vmcnt(0)" ::: "memory");
    }
    __builtin_amdgcn_s_barrier();      // all waves' tile-k loads done
    __builtin_amdgcn_sched_barrier(0); // no ds_read hoisting above the wait
    if (k < 14) {                      // issue tile k+2 (its buffer was last
      const int nb = (k + 2) % 3;      //  read at iter k-1; barrier proves done)
      GLOAD_LDS(xb + (size_t)((k + 2) * 16 + lrow) * HW + csub,
                &lx[nb][wv << 2][0], 16);
    }
    const float* lxk = &lx[k % 3][0][0];
    const float* wr0 = w1f + (k << 10) + (wv << 4);
#pragma unroll
    for (int c = 0; c < 16; ++c) {
      const float xv = lxk[(c << 6) + px];
      const float* wr = wr0 + (c << 6);            // wave-uniform -> s_load x4
      const float4 wa = *(const float4*)(wr + 0);
      const float4 wb = *(const float4*)(wr + 4);
      const float4 wc = *(const float4*)(wr + 8);
      const float4 wd = *(const float4*)(wr + 12);
      acc[0]  = fmaf(xv, wa.x, acc[0]);
      acc[1]  = fmaf(xv, wa.y, acc[1]);
      acc[2]  = fmaf(xv, wa.z, acc[2]);
      acc[3]  = fmaf(xv, wa.w, acc[3]);
      acc[4]  = fmaf(xv, wb.x, acc[4]);
      acc[5]  = fmaf(xv, wb.y, acc[5]);
      acc[6]  = fmaf(xv, wb.z, acc[6]);
      acc[7]  = fmaf(xv, wb.w, acc[7]);
      acc[8]  = fmaf(xv, wc.x, acc[8]);
      acc[9]  = fmaf(xv, wc.y, acc[9]);
      acc[10] = fmaf(xv, wc.z, acc[10]);
      acc[11] = fmaf(xv, wc.w, acc[11]);
      acc[12] = fmaf(xv, wd.x, acc[12]);
      acc[13] = fmaf(xv, wd.y, acc[13]);
      acc[14] = fmaf(xv, wd.z, acc[14]);
      acc[15] = fmaf(xv, wd.w, acc[15]);
    }
  }

#pragma unroll
  for (int j = 0; j < 16; ++j) {
    const int o = (wv << 4) + j;
    t[(size_t)o * NPIX + px0 + px] = fmaxf(acc[j] + bias1[o], 0.0f);
  }
}

// ---------------------------------------------------------------------------
// conv2 + involution. Block = ONE wave = one (pixel chunk, group). Grid 12544.
// bid remap: r=bid&7, kq=bid>>3, g=kq&15, pc=(kq>>4)*8+r -> all 16 g-waves of
// a chunk share bid%8 = pc%8 (= conv1 writer's XCD) and sit 8 apart.
// t column -> registers (2x32 chunks); all loads use uniform-base + unsigned
// 32-bit lane offset so the channel/row constants fold into SGPR adds.
// No LDS, no barriers. w2/b2 via wave-uniform s_load (scalar pipe).
// ---------------------------------------------------------------------------
#define LOADCH(dst, ch)                                                   \
  {                                                                       \
    _Pragma("unroll")                                                     \
    for (int kk = 0; kk < NKK; ++kk)                                      \
      dst[kk] = xg[(unsigned)((ch) * HW) + off[kk]];                      \
  }
#define CONSUME(src, ch)                                                  \
  {                                                                       \
    float s0 = wk[0] * src[0];                                            \
    float s1 = wk[1] * src[1];                                            \
    float s2 = wk[2] * src[2];                                            \
    s0 = fmaf(wk[3], src[3], s0);                                         \
    s1 = fmaf(wk[4], src[4], s1);                                         \
    s2 = fmaf(wk[5], src[5], s2);                                         \
    s0 = fmaf(wk[6], src[6], s0);                                         \
    s1 = fmaf(wk[7], src[7], s1);                                         \
    s2 = fmaf(wk[8], src[8], s2);                                         \
    og[(unsigned)((ch) * HW) + hw] = s0 + s1 + s2;                        \
  }

__global__ __launch_bounds__(64, 4) void conv2_inv_kernel(
    const float* __restrict__ x,
    const float* __restrict__ t,
    const float* __restrict__ w2,
    const float* __restrict__ b2,
    float* __restrict__ out) {
  const unsigned px = threadIdx.x;     // 0..63

  const int bid = blockIdx.x;
  const int r   = bid & 7;
  const int kq  = bid >> 3;
  const int g   = kq & 15;                 // group (wave-uniform)
  const int pc  = ((kq >> 4) << 3) + r;    // pixel chunk 0..783

  const int b   = pc / 49;                 // 49 chunks per batch
  const unsigned hw = (unsigned)(pc - b * 49) * PXT + px;   // within batch

  const float* __restrict__ tb = t + (size_t)pc * PXT;      // uniform base

  // ---- t column, chunk A (o 0..31) then chunk B (o 32..63) ----
  float tv[32], tw[32];
#pragma unroll
  for (int o = 0; o < 32; ++o) tv[o] = tb[(unsigned)(o * NPIX) + px];
#pragma unroll
  for (int o = 0; o < 32; ++o) tw[o] = tb[(unsigned)((o + 32) * NPIX) + px];

  // ---- tap geometry (VALU, overlaps loads) ----
  const int h = hw / Wn;
  const int w = hw - h * Wn;

  unsigned off[NKK];
  unsigned vmask = 0;
#pragma unroll
  for (int kk = 0; kk < NKK; ++kk) {
    const int di  = kk / 3 - 1;
    const int dj  = kk % 3 - 1;
    const int h2  = h + di;
    const int w2v = w + dj;
    const bool valid = ((unsigned)h2 < (unsigned)Hn) && ((unsigned)w2v < (unsigned)Wn);
    off[kk] = valid ? (unsigned)(h2 * Wn + w2v) : hw;
    vmask |= (valid ? 1u : 0u) << kk;
  }

  // ---- conv2: a[9] accumulated from register t + scalar-pipe w2 ----
  float a[NKK];
#pragma unroll
  for (int kk = 0; kk < NKK; ++kk) a[kk] = b2[g * NKK + kk];   // uniform s_load

  const float* wg = w2 + (size_t)g * (NKK * MID);              // uniform base

#pragma unroll
  for (int o4 = 0; o4 < 32; o4 += 4) {
#pragma unroll
    for (int kk = 0; kk < NKK; ++kk) {
      const float4 w4 = *(const float4*)(wg + (kk << 6) + o4); // s_load x4
      a[kk] = fmaf(tv[o4 + 3], w4.w,
              fmaf(tv[o4 + 2], w4.z,
              fmaf(tv[o4 + 1], w4.y,
              fmaf(tv[o4 + 0], w4.x, a[kk]))));
    }
  }

  // issue first 4 channels' taps here: latency hides under chunk-B FMAs
  const float* __restrict__ xg = x + (size_t)b * CHW + (size_t)(g * GSZ) * HW;
  float* __restrict__ og = out + (size_t)b * CHW + (size_t)(g * GSZ) * HW;
  float p0[NKK], p1[NKK], p2[NKK], p3[NKK];
  LOADCH(p0, 0)
  LOADCH(p1, 1)
  LOADCH(p2, 2)
  LOADCH(p3, 3)

#pragma unroll
  for (int o4 = 0; o4 < 32; o4 += 4) {
#pragma unroll
    for (int kk = 0; kk < NKK; ++kk) {
      const float4 w4 = *(const float4*)(wg + (kk << 6) + 32 + o4);
      a[kk] = fmaf(tw[o4 + 3], w4.w,
              fmaf(tw[o4 + 2], w4.z,
              fmaf(tw[o4 + 1], w4.y,
              fmaf(tw[o4 + 0], w4.x, a[kk]))));
    }
  }

  float wk[NKK];
#pragma unroll
  for (int kk = 0; kk < NKK; ++kk)
    wk[kk] = ((vmask >> kk) & 1u) ? a[kk] : 0.0f;

  // ---- involution: 4-deep pipeline (stores hoistable past loads:
  //      x/out are distinct __restrict__ params) ----
  CONSUME(p0, 0)  LOADCH(p0, 4)
  CONSUME(p1, 1)  LOADCH(p1, 5)
  CONSUME(p2, 2)  LOADCH(p2, 6)
  CONSUME(p3, 3)  LOADCH(p3, 7)
  CONSUME(p0, 4)  LOADCH(p0, 8)
  CONSUME(p1, 5)  LOADCH(p1, 9)
  CONSUME(p2, 6)  LOADCH(p2, 10)
  CONSUME(p3, 7)  LOADCH(p3, 11)
  CONSUME(p0, 8)  LOADCH(p0, 12)
  CONSUME(p1, 9)  LOADCH(p1, 13)
  CONSUME(p2, 10) LOADCH(p2, 14)
  CONSUME(p3, 11) LOADCH(p3, 15)
  CONSUME(p0, 12)
  CONSUME(p1, 13)
  CONSUME(p2, 14)
  CONSUME(p3, 15)
}

// ---------------------------------------------------------------------------
extern "C" void kernel_launch(void* const* d_in, const int* in_sizes, int n_in,
                              void* d_out, int out_size, void* d_ws, size_t ws_size,
                              hipStream_t stream) {
  const float* x     = (const float*)d_in[0];
  const float* w1    = (const float*)d_in[1];
  const float* gamma = (const float*)d_in[2];
  const float* beta  = (const float*)d_in[3];
  const float* mean  = (const float*)d_in[4];
  const float* var   = (const float*)d_in[5];
  const float* w2    = (const float*)d_in[6];
  const float* b2    = (const float*)d_in[7];
  float* out = (float*)d_out;

  // workspace: t (64 x 50176 fp32 = 12.85 MB) | w1f (64 KB) | bias1 (256 B)
  char* ws = (char*)d_ws;
  float* t     = (float*)ws;
  float* w1f   = (float*)(ws + (size_t)MID * NPIX * 4);
  float* bias1 = (float*)(ws + (size_t)MID * NPIX * 4 + (size_t)MID * Cn * 4);

  prep_kernel<<<(MID * Cn + MID + 255) / 256, 256, 0, stream>>>(
      w1, gamma, beta, mean, var, w1f, bias1);
  conv1_kernel<<<NPIX / PXT, 256, 0, stream>>>(x, w1f, bias1, t);
  conv2_inv_kernel<<<NPIX / PXT * NG, 64, 0, stream>>>(x, t, w2, b2, out);
}

// Round 12
// 176.969 us; speedup vs baseline: 1.0134x; 1.0134x over previous
//
#include <hip/hip_runtime.h>

// Involution: B=16, C=256, H=W=56, mid=64, GROUPS=16, GROUP_SIZE=16, K=3 (KK=9)
// All fp32. Output (16,256,56,56).
//
// This revision: t stored TRANSPOSED (t^T[pixel][o], 64 contiguous floats
// per pixel).
//  conv1     : R10 internals (acc[16], triple buffer, counted vmcnt); epilogue
//              now 4 dwordx4 stores per lane (contig 64B per pixel).
//  conv2_inv : NO LDS, NO barriers. Lane's t column = 16 global_load_dwordx4
//              with immediate offsets off ONE base (vs R11's 64 strided
//              scalar loads - the diagnosed regression cause). Consumed in
//              4 chunks of 16 so loads hide under 144-FMA chunks. Tap
//              pipeline byte-identical to R10's proven code.

#define Cn    256
#define MID   64
#define Hn    56
#define Wn    56
#define HW    3136
#define Bn    16
#define NPIX  (Bn * HW)       // 50176
#define CHW   (Cn * HW)
#define NKK   9
#define NG    16
#define GSZ   16
#define PXT   64              // pixels per chunk (49 chunks/batch, 784 total)
#define BN_EPS 1e-5f

// async global->LDS: per-lane global src, wave-uniform LDS base + lane*size
#define GLOAD_LDS(src, dst, sz)                                                        \
  __builtin_amdgcn_global_load_lds(                                                    \
      (const __attribute__((address_space(1))) void*)(src),                            \
      (__attribute__((address_space(3))) void*)(dst), (sz), 0, 0)

// ---------------------------------------------------------------------------
// prep: w1f[c*64+o] = w1[o*256+c] * scale[o];  bias1[o] = beta[o]-mean[o]*scale[o]
// ---------------------------------------------------------------------------
__global__ __launch_bounds__(256) void prep_kernel(
    const float* __restrict__ w1,
    const float* __restrict__ gamma,
    const float* __restrict__ beta,
    const float* __restrict__ mean,
    const float* __restrict__ var,
    float* __restrict__ w1f,
    float* __restrict__ bias1) {
  int idx = blockIdx.x * 256 + threadIdx.x;
  if (idx < MID * Cn) {
    int c = idx >> 6;
    int o = idx & 63;
    float scale = gamma[o] / sqrtf(var[o] + BN_EPS);
    w1f[idx] = w1[o * Cn + c] * scale;
  } else if (idx < MID * Cn + MID) {
    int o = idx - MID * Cn;
    float scale = gamma[o] / sqrtf(var[o] + BN_EPS);
    bias1[o] = beta[o] - mean[o] * scale;
  }
}

// ---------------------------------------------------------------------------
// conv1: t^T[pix][o] = relu(bias1[o] + sum_c x[b,c,pix] * w1f[c*64+o])
// Block = 64 px x ALL 64 outputs (grid 784). Wave wv -> outputs wv*16..+15.
// Per c: 1 ds_read_b32 (x) + 4 wave-uniform s_load_dwordx4 (weights) + 16 FMA.
// x tiles: TRIPLE-buffered LDS, counted vmcnt(1) -> loads span barriers.
// Epilogue: lane px stores its 16 outputs as 4 dwordx4 at t^T[pix][wv*16..].
// ---------------------------------------------------------------------------
__global__ __launch_bounds__(256) void conv1_kernel(
    const float* __restrict__ x,
    const float* __restrict__ w1f,
    const float* __restrict__ bias1,
    float* __restrict__ t) {
  __shared__ __align__(16) float lx[3][16][PXT];   // 12 KB triple buffer

  const int tid = threadIdx.x;
  const int px  = tid & 63;
  const int wv  = __builtin_amdgcn_readfirstlane(tid >> 6);   // 0..3

  const int bid = blockIdx.x;          // pc == bid; XCD = bid%8 (matches conv2)
  const int px0 = bid * PXT;
  const int b   = px0 / HW;
  const int hw0 = px0 - b * HW;
  const float* xb = x + (size_t)b * CHW + hw0;

  const int rsub = px >> 4;            // 0..3
  const int csub = (px & 15) << 2;     // 0,4,..,60
  const int lrow = (wv << 2) + rsub;   // lane's row within the 16-row tile

  // prologue: issue tiles 0 and 1 (stay in flight into the loop)
  GLOAD_LDS(xb + (size_t)lrow * HW + csub, &lx[0][wv << 2][0], 16);
  GLOAD_LDS(xb + (size_t)(16 + lrow) * HW + csub, &lx[1][wv << 2][0], 16);

  float acc[16];
#pragma unroll
  for (int j = 0; j < 16; ++j) acc[j] = 0.0f;

  for (int k = 0; k < 16; ++k) {
    // wait tile k only; tile k+1's load stays outstanding (counted vmcnt).
    if (k < 15) {
      asm volatile("s_waitcnt vmcnt(1)" ::: "memory");
    } else {
      asm volatile("s_waitcnt vmcnt(0)" ::: "memory");
    }
    __builtin_amdgcn_s_barrier();      // all waves' tile-k loads done
    __builtin_amdgcn_sched_barrier(0); // no ds_read hoisting above the wait
    if (k < 14) {                      // issue tile k+2 (its buffer was last
      const int nb = (k + 2) % 3;      //  read at iter k-1; barrier proves done)
      GLOAD_LDS(xb + (size_t)((k + 2) * 16 + lrow) * HW + csub,
                &lx[nb][wv << 2][0], 16);
    }
    const float* lxk = &lx[k % 3][0][0];
    const float* wr0 = w1f + (k << 10) + (wv << 4);
#pragma unroll
    for (int c = 0; c < 16; ++c) {
      const float xv = lxk[(c << 6) + px];
      const float* wr = wr0 + (c << 6);            // wave-uniform -> s_load x4
      const float4 wa = *(const float4*)(wr + 0);
      const float4 wb = *(const float4*)(wr + 4);
      const float4 wc = *(const float4*)(wr + 8);
      const float4 wd = *(const float4*)(wr + 12);
      acc[0]  = fmaf(xv, wa.x, acc[0]);
      acc[1]  = fmaf(xv, wa.y, acc[1]);
      acc[2]  = fmaf(xv, wa.z, acc[2]);
      acc[3]  = fmaf(xv, wa.w, acc[3]);
      acc[4]  = fmaf(xv, wb.x, acc[4]);
      acc[5]  = fmaf(xv, wb.y, acc[5]);
      acc[6]  = fmaf(xv, wb.z, acc[6]);
      acc[7]  = fmaf(xv, wb.w, acc[7]);
      acc[8]  = fmaf(xv, wc.x, acc[8]);
      acc[9]  = fmaf(xv, wc.y, acc[9]);
      acc[10] = fmaf(xv, wc.z, acc[10]);
      acc[11] = fmaf(xv, wc.w, acc[11]);
      acc[12] = fmaf(xv, wd.x, acc[12]);
      acc[13] = fmaf(xv, wd.y, acc[13]);
      acc[14] = fmaf(xv, wd.z, acc[14]);
      acc[15] = fmaf(xv, wd.w, acc[15]);
    }
  }

  // epilogue: transposed store -- lane's 16 outputs are contiguous at
  // t^T[(px0+px)*64 + wv*16 .. +15]  (4 dwordx4, each lane one 64B line)
  float4* tp = (float4*)(t + ((size_t)(px0 + px) << 6) + (wv << 4));
#pragma unroll
  for (int q = 0; q < 4; ++q) {
    const int o = (wv << 4) + (q << 2);
    tp[q] = make_float4(fmaxf(acc[q * 4 + 0] + bias1[o + 0], 0.0f),
                        fmaxf(acc[q * 4 + 1] + bias1[o + 1], 0.0f),
                        fmaxf(acc[q * 4 + 2] + bias1[o + 2], 0.0f),
                        fmaxf(acc[q * 4 + 3] + bias1[o + 3], 0.0f));
  }
}

// ---------------------------------------------------------------------------
// conv2 + involution. Block = 64 px x ONE group-quad, grid 3136. NO LDS,
// NO barriers -- waves fully independent.
// bid decode: pc = (bid>>5)*8 + (bid&7), gq = (bid>>3)&3  -> all 4 quads of a
// pc share bid%8 (XCD-local t, same XCD as the conv1 writer block).
// t column: 16 dwordx4 with imm offsets off ONE per-lane base, consumed in
// 4 chunks of 16 o-values (next chunk's loads hide under 144 FMAs).
// Taps: R10's proven 4-deep pipeline, res[16] batched stores.
// ---------------------------------------------------------------------------
#define LOADCH(dst, ch)                                                   \
  {                                                                       \
    const float* _xp = xcg + (size_t)(ch) * HW;                           \
    _Pragma("unroll")                                                     \
    for (int kk = 0; kk < NKK; ++kk) dst[kk] = _xp[off[kk]];              \
  }
#define CONSUME(src, ch)                                                  \
  {                                                                       \
    float s0 = wk[0] * src[0];                                            \
    float s1 = wk[1] * src[1];                                            \
    float s2 = wk[2] * src[2];                                            \
    s0 = fmaf(wk[3], src[3], s0);                                         \
    s1 = fmaf(wk[4], src[4], s1);                                         \
    s2 = fmaf(wk[5], src[5], s2);                                         \
    s0 = fmaf(wk[6], src[6], s0);                                         \
    s1 = fmaf(wk[7], src[7], s1);                                         \
    s2 = fmaf(wk[8], src[8], s2);                                         \
    res[ch] = s0 + s1 + s2;                                               \
  }
// conv2 chunk Q (o = Q*16 .. Q*16+15): 4 float4 of t x 9 kk
#define C2CHUNK(Q)                                                        \
  {                                                                       \
    const float4 ta = tc[(Q) * 4 + 0];                                    \
    const float4 tb_ = tc[(Q) * 4 + 1];                                   \
    const float4 tcc = tc[(Q) * 4 + 2];                                   \
    const float4 td = tc[(Q) * 4 + 3];                                    \
    _Pragma("unroll")                                                     \
    for (int kk = 0; kk < NKK; ++kk) {                                    \
      const float* _w = wg + (kk << 6) + (Q) * 16;                        \
      const float4 wA = *(const float4*)(_w + 0);                         \
      const float4 wB = *(const float4*)(_w + 4);                         \
      const float4 wC = *(const float4*)(_w + 8);                         \
      const float4 wD = *(const float4*)(_w + 12);                        \
      float s = fmaf(ta.x, wA.x, a[kk]);                                  \
      s = fmaf(ta.y, wA.y, s);  s = fmaf(ta.z, wA.z, s);                  \
      s = fmaf(ta.w, wA.w, s);  s = fmaf(tb_.x, wB.x, s);                 \
      s = fmaf(tb_.y, wB.y, s); s = fmaf(tb_.z, wB.z, s);                 \
      s = fmaf(tb_.w, wB.w, s); s = fmaf(tcc.x, wC.x, s);                 \
      s = fmaf(tcc.y, wC.y, s); s = fmaf(tcc.z, wC.z, s);                 \
      s = fmaf(tcc.w, wC.w, s); s = fmaf(td.x, wD.x, s);                  \
      s = fmaf(td.y, wD.y, s);  s = fmaf(td.z, wD.z, s);                  \
      s = fmaf(td.w, wD.w, s);                                            \
      a[kk] = s;                                                          \
    }                                                                     \
  }

__global__ __launch_bounds__(256, 4) void conv2_inv_kernel(
    const float* __restrict__ x,
    const float* __restrict__ t,
    const float* __restrict__ w2,
    const float* __restrict__ b2,
    float* __restrict__ out) {
  const int tid = threadIdx.x;
  const int px  = tid & 63;
  const int wv  = __builtin_amdgcn_readfirstlane(tid >> 6);   // 0..3

  const int bid = blockIdx.x;
  const int pc  = ((bid >> 5) << 3) + (bid & 7);   // pixel chunk 0..783
  const int gq  = (bid >> 3) & 3;                  // group quad 0..3
  const int g   = (gq << 2) + wv;                  // wave's group (uniform)

  const int px0 = pc * PXT;
  const int b   = px0 / HW;
  const int hw0 = px0 - b * HW;

  // lane's t column: 64 contiguous floats (one 64B-line-aligned 256B run)
  const float4* __restrict__ tc = (const float4*)(t + ((size_t)(px0 + px) << 6));

  // ---- tap geometry ----
  const int hw = hw0 + px;
  const int h  = hw / Wn;
  const int w  = hw - h * Wn;

  int off[NKK];
  unsigned vmask = 0;
#pragma unroll
  for (int kk = 0; kk < NKK; ++kk) {
    const int di  = kk / 3 - 1;
    const int dj  = kk % 3 - 1;
    const int h2  = h + di;
    const int w2v = w + dj;
    const bool valid = ((unsigned)h2 < (unsigned)Hn) && ((unsigned)w2v < (unsigned)Wn);
    off[kk] = valid ? (h2 * Wn + w2v) : hw;
    vmask |= (valid ? 1u : 0u) << kk;
  }

  // ---- conv2: per-pixel kernel weights for group g, registers only ----
  float a[NKK];
#pragma unroll
  for (int kk = 0; kk < NKK; ++kk) a[kk] = b2[g * NKK + kk];   // uniform s_load

  const float* wg = w2 + (size_t)g * (NKK * MID);              // uniform base

  C2CHUNK(0)
  C2CHUNK(1)
  C2CHUNK(2)
  C2CHUNK(3)

  float wk[NKK];
#pragma unroll
  for (int kk = 0; kk < NKK; ++kk)
    wk[kk] = ((vmask >> kk) & 1u) ? a[kk] : 0.0f;

  // ---- involution: R10's 4-deep pipeline, results batched ----
  const float* xcg = x + (size_t)b * CHW + (size_t)(g * GSZ) * HW;
  float p0[NKK], p1[NKK], p2[NKK], p3[NKK];
  float res[GSZ];

  LOADCH(p0, 0)
  LOADCH(p1, 1)
  LOADCH(p2, 2)
  LOADCH(p3, 3)

  CONSUME(p0, 0)  LOADCH(p0, 4)
  CONSUME(p1, 1)  LOADCH(p1, 5)
  CONSUME(p2, 2)  LOADCH(p2, 6)
  CONSUME(p3, 3)  LOADCH(p3, 7)
  CONSUME(p0, 4)  LOADCH(p0, 8)
  CONSUME(p1, 5)  LOADCH(p1, 9)
  CONSUME(p2, 6)  LOADCH(p2, 10)
  CONSUME(p3, 7)  LOADCH(p3, 11)
  CONSUME(p0, 8)  LOADCH(p0, 12)
  CONSUME(p1, 9)  LOADCH(p1, 13)
  CONSUME(p2, 10) LOADCH(p2, 14)
  CONSUME(p3, 11) LOADCH(p3, 15)
  CONSUME(p0, 12)
  CONSUME(p1, 13)
  CONSUME(p2, 14)
  CONSUME(p3, 15)

  // ---- batched stores (coalesced across lanes) ----
  float* ob = out + (size_t)b * CHW + (size_t)(g * GSZ) * HW + hw;
#pragma unroll
  for (int cc = 0; cc < GSZ; ++cc)
    ob[(size_t)cc * HW] = res[cc];
}

// ---------------------------------------------------------------------------
extern "C" void kernel_launch(void* const* d_in, const int* in_sizes, int n_in,
                              void* d_out, int out_size, void* d_ws, size_t ws_size,
                              hipStream_t stream) {
  const float* x     = (const float*)d_in[0];
  const float* w1    = (const float*)d_in[1];
  const float* gamma = (const float*)d_in[2];
  const float* beta  = (const float*)d_in[3];
  const float* mean  = (const float*)d_in[4];
  const float* var   = (const float*)d_in[5];
  const float* w2    = (const float*)d_in[6];
  const float* b2    = (const float*)d_in[7];
  float* out = (float*)d_out;

  // workspace: t^T (50176 x 64 fp32 = 12.85 MB) | w1f (64 KB) | bias1 (256 B)
  char* ws = (char*)d_ws;
  float* t     = (float*)ws;
  float* w1f   = (float*)(ws + (size_t)MID * NPIX * 4);
  float* bias1 = (float*)(ws + (size_t)MID * NPIX * 4 + (size_t)MID * Cn * 4);

  prep_kernel<<<(MID * Cn + MID + 255) / 256, 256, 0, stream>>>(
      w1, gamma, beta, mean, var, w1f, bias1);
  conv1_kernel<<<NPIX / PXT, 256, 0, stream>>>(x, w1f, bias1, t);
  conv2_inv_kernel<<<NPIX / PXT * 4, 256, 0, stream>>>(x, t, w2, b2, out);
}